// Round 6
// baseline (187.440 us; speedup 1.0000x reference)
//
#include <hip/hip_runtime.h>

#define N_ROWS 16384
#define K_CB   8192
#define D_DIM  64
#define NSPLIT 8
#define SPLIT_K (K_CB / NSPLIT)          // 1024
#define STAGE  64                        // codebook rows per LDS stage (two 32-n tiles)
#define NSTAGES (SPLIT_K / STAGE)        // 16  -> slot = 2*s+u in [0,32): 5 bits
#define BLKT   256                       // 4 waves per block, 1 m-tile (32 rows) per wave

typedef unsigned short u16;
typedef unsigned int   u32;
typedef unsigned long long u64;
typedef __attribute__((ext_vector_type(8)))  short short8v;  // 8 bf16 (4 VGPRs)
typedef __attribute__((ext_vector_type(16))) float f32x16;   // 32x32 MFMA C/D

static __device__ __forceinline__ u16 f2bf(float f) {        // RNE fp32->bf16
    unsigned u = __float_as_uint(f);
    return (u16)((u + 0x7FFFu + ((u >> 16) & 1u)) >> 16);
}

// ---- kernel 0: codebook prep. bf16 cast + 0.5*||c||^2; zero slice counters.
// Single-product bf16 scoring: residual error (~0.02 std) is absorbed by the
// exact fp32 top-2 rescore (top-score spacing ~2.4 for 8192 gaussian
// codewords: huge margin).
__global__ void vq_prep_kernel(const float* __restrict__ cb,
                               u16* __restrict__ cb_hi, float* __restrict__ hcsq,
                               u32* __restrict__ cnt)
{
    if (blockIdx.x == 0 && threadIdx.x < N_ROWS / 128)
        cnt[threadIdx.x] = 0;                              // ws is poisoned: must zero
    const int wave = threadIdx.x >> 6;
    const int lane = threadIdx.x & 63;
#pragma unroll
    for (int rr = 0; rr < 2; ++rr) {
        const int r = blockIdx.x * 8 + wave * 2 + rr;
        const float v = cb[r * D_DIM + lane];
        cb_hi[r * D_DIM + lane] = f2bf(v);
        float d = v * v;
#pragma unroll
        for (int m = 1; m < 64; m <<= 1) d += __shfl_xor(d, m, 64);
        if (lane == 0) hcsq[r] = 0.5f * d;
    }
}

// ---- kernel 1: 32x32x16 MFMA scores, 1 m-tile/wave (32 rows), 4 waves,
//      single bf16 product, float-key argmax + exact fp32 top-2 rescore,
//      FUSED gather (last y-block per x-slice writes the 128 output rows) ----
// R6 = R3 body EXACTLY (proven 46us, VGPR 52, zero spill, NSPLIT=8 — R5
// proved NSPLIT=16 pays ~5us fixed cost per extra block) + fused gather.
// score(m,n) = dot(x_m, c_n) - 0.5||c_n||^2 ; argmin dist == argmax score.
// A operand: m=lane&31, k=(lane>>5)*8+j. B operand: n=lane&31, k=(lane>>5)*8+j.
// C/D: col(n)=lane&31, row(m)=(reg&3)+8*(reg>>2)+4*(lane>>5)   [m74/m101].
// Key: bits(score) & ~31 | slot, kept with v_max_f32 (<=31 ulp perturbation,
// absorbed by exact top-2 rescore); slot = 2*stage+subtile recovers cidx.
__global__ __launch_bounds__(BLKT, 4) void vq_mfma_kernel(
    const float* __restrict__ enc, const float* __restrict__ cb,
    const u16* __restrict__ cb_hi, const float* __restrict__ hcsq,
    u64* __restrict__ winner, u32* __restrict__ cnt, float* __restrict__ outp)
{
    // loop phase: ldsb 2 bufs x 8KB (4096 u32) | lds_h 4KB (1024 u32) = 20 KB
    // epilogue:   keys[128][33] (4224 u32) reuses front; idxb at 4352; flag 5000.
    __shared__ __align__(16) u32 smem[5120];
    u16*   ldsb  = (u16*)smem;                 // [0, 4096) u32
    float* lds_h = (float*)(smem + 4096);      // [4096, 5120) u32
    u32*   keys  = smem;                       // epilogue reuse [0, 4224)
    u32*   idxb  = smem + 4352;                // epilogue [4352, 4608)

    const int tid  = threadIdx.x;
    const int w    = tid >> 6;                             // 0..3
    const int lane = tid & 63;
    const int n32  = lane & 31;
    const int lh   = lane >> 5;
    const int B0   = blockIdx.y * SPLIT_K;
    const int rowbase = blockIdx.x * 128 + w * 32;         // 32 m-rows per wave

    // ---- A fragments: 1 m-tile x 4 k-chunks, converted once ----
    short8v a_hi[4];
    {
        const float* arow = enc + (size_t)(rowbase + n32) * D_DIM + lh * 8;
#pragma unroll
        for (int c = 0; c < 4; ++c) {
            const float4 u0 = ((const float4*)(arow + c * 16))[0];
            const float4 u1 = ((const float4*)(arow + c * 16))[1];
            const float vv[8] = {u0.x,u0.y,u0.z,u0.w,u1.x,u1.y,u1.z,u1.w};
            short8v h8;
#pragma unroll
            for (int j = 0; j < 8; ++j) h8[j] = (short)f2bf(vv[j]);
            a_hi[c] = h8;
        }
    }

    // ---- split's hcsq into LDS (once) ----
#pragma unroll
    for (int i = 0; i < SPLIT_K / BLKT; ++i)               // 4 iters
        lds_h[tid + i * BLKT] = hcsq[B0 + tid + i * BLKT];

    // ---- DMA: 8 granules/stage = 4 waves x 2; wave owns (u, c-parity) ----
    // granule slot = lane (n=lane&31, octet=2c+lh) -> contiguous b128 dest.
    const int uu = w & 1;                                  // 32-n subtile
    const int cp = w >> 1;                                 // c parity
    const u16* gbase = cb_hi + (size_t)B0 * D_DIM;

#define DMA_STAGE(buf_, s_)                                                      \
    do {                                                                         \
        _Pragma("unroll")                                                        \
        for (int i_ = 0; i_ < 2; ++i_) {                                         \
            const int c_ = cp + 2 * i_;                                          \
            __builtin_amdgcn_global_load_lds(                                    \
                (const __attribute__((address_space(1))) void*)                  \
                    (gbase + ((size_t)(s_) * STAGE + uu * 32 + n32) * D_DIM      \
                           + (2 * c_ + lh) * 8),                                 \
                (__attribute__((address_space(3))) void*)                        \
                    (ldsb + (buf_) * 4096 + uu * 2048 + c_ * 512),               \
                16, 0, 0);                                                       \
        }                                                                        \
    } while (0)

    DMA_STAGE(0, 0);
    __syncthreads();                                       // stage 0 resident

    f32x16 z;
#pragma unroll
    for (int r = 0; r < 16; ++r) z[r] = 0.f;               // never written: chain seed

    float bkey[16];
#pragma unroll
    for (int r = 0; r < 16; ++r) bkey[r] = -INFINITY;

    for (int s = 0; s < NSTAGES; ++s) {
        const int buf = s & 1;
        DMA_STAGE(buf ^ 1, (s + 1) & (NSTAGES - 1));       // async prefetch (wrap ok)

#pragma unroll
        for (int u = 0; u < 2; ++u) {                      // two 32-n subtiles
            const u16* bb = ldsb + buf * 4096 + u * 2048;
            short8v bh[4];
#pragma unroll
            for (int c = 0; c < 4; ++c)
                bh[c] = *(const short8v*)(bb + c * 512 + lane * 8);
            const float h = lds_h[s * STAGE + u * 32 + n32];
            const u32 slot = (u32)(s * 2 + u);             // 5 bits

            f32x16 acc;
            acc = __builtin_amdgcn_mfma_f32_32x32x16_bf16(a_hi[0], bh[0], z,   0,0,0);
            acc = __builtin_amdgcn_mfma_f32_32x32x16_bf16(a_hi[1], bh[1], acc, 0,0,0);
            acc = __builtin_amdgcn_mfma_f32_32x32x16_bf16(a_hi[2], bh[2], acc, 0,0,0);
            acc = __builtin_amdgcn_mfma_f32_32x32x16_bf16(a_hi[3], bh[3], acc, 0,0,0);

#pragma unroll
            for (int r = 0; r < 16; ++r) {
                const float sc = acc[r] - h;
                const u32 kb = (__float_as_uint(sc) & 0xFFFFFFE0u) | slot;
                bkey[r] = fmaxf(bkey[r], __uint_as_float(kb));
            }
        }
        __syncthreads();   // all waves done reading buf; prefetch drained (vmcnt0)
    }
#undef DMA_STAGE

    // ---- per-class winners -> keys[row][cls] in LDS (reuses ldsb region) ----
#pragma unroll
    for (int r = 0; r < 16; ++r) {
        const int m = (r & 3) + 8 * (r >> 2) + 4 * lh;
        keys[(w * 32 + m) * 33 + n32] = __float_as_uint(bkey[r]);
    }
    __syncthreads();

    // ---- top-2 of 32 classes (1 thread per row), handoff via LDS ----
    if (tid < 128) {
        float k1 = -INFINITY, k2 = -INFINITY; int c1i = 0, c2i = 0;
#pragma unroll
        for (int cls = 0; cls < 32; ++cls) {
            const float kf = __uint_as_float(keys[tid * 33 + cls]);
            if (kf > k1)      { k2 = k1; c2i = c1i; k1 = kf; c1i = cls; }
            else if (kf > k2) { k2 = kf; c2i = cls; }
        }
        idxb[tid * 2 + 0] = (u32)(B0 + (int)(__float_as_uint(k1) & 31u) * 32 + c1i);
        idxb[tid * 2 + 1] = (u32)(B0 + (int)(__float_as_uint(k2) & 31u) * 32 + c2i);
    }
    __syncthreads();

    // ---- exact fp32 rescore, 2 threads/row (one candidate each) ----
    {
        const int row  = tid >> 1;
        const int grow = blockIdx.x * 128 + row;
        const int idx  = (int)idxb[tid];

        const float4* xp = (const float4*)(enc + (size_t)grow * D_DIM);
        const float4* cp4 = (const float4*)(cb + (size_t)idx  * D_DIM);
        float d = 0.f;
#pragma unroll
        for (int i = 0; i < 16; ++i) {
            const float4 xv = xp[i], v = cp4[i];
            float t;
            t = xv.x - v.x; d = fmaf(t, t, d);
            t = xv.y - v.y; d = fmaf(t, t, d);
            t = xv.z - v.z; d = fmaf(t, t, d);
            t = xv.w - v.w; d = fmaf(t, t, d);
        }
        // (distbits, idx) packed: u64 min == (min dist, then min idx) = jnp first-min.
        // 0xAAAA... ws poison exceeds any packed value (dist sign bit 0): free sentinel.
        atomicMin(winner + grow, ((u64)__float_as_uint(d) << 32) | (u32)idx);
    }

    // ---- fused gather: last y-block to finish this x-slice writes output ----
    // Release: each thread fences its own atomicMin BEFORE the barrier, so
    // tid0's counter RMW is ordered after all 512 winner RMWs of this block.
    __threadfence();
    __syncthreads();
    if (tid == 0) {
        const u32 old = atomicAdd(cnt + blockIdx.x, 1u);   // device scope
        smem[5000] = (old == (u32)(NSPLIT - 1)) ? 1u : 0u;
    }
    __syncthreads();
    if (smem[5000]) {                                      // block-uniform branch
        __threadfence();                                   // acquire side
        if (tid < 128) {
            const u64 wv = __hip_atomic_load(winner + blockIdx.x * 128 + tid,
                                             __ATOMIC_RELAXED,
                                             __HIP_MEMORY_SCOPE_AGENT);
            idxb[tid] = (u32)(wv & 0xFFFFFFFFu);
        }
        __syncthreads();
#pragma unroll
        for (int k = 0; k < 8; ++k) {                      // 128 rows x 16 float4
            const int g   = tid + k * 256;
            const int row = g >> 4;
            const int c4  = g & 15;
            ((float4*)(outp + (size_t)(blockIdx.x * 128 + row) * D_DIM))[c4] =
                ((const float4*)(cb + (size_t)idxb[row] * D_DIM))[c4];
        }
    }
}

extern "C" void kernel_launch(void* const* d_in, const int* in_sizes, int n_in,
                              void* d_out, int out_size, void* d_ws, size_t ws_size,
                              hipStream_t stream) {
    const float* enc = (const float*)d_in[0];   // 16384 x 64 fp32
    const float* cb  = (const float*)d_in[1];   // 8192 x 64 fp32
    float* out = (float*)d_out;

    // ws layout (~1.16 MB): cb_hi | hcsq | winner | cnt
    u16* cb_hi  = (u16*)d_ws;                       // 1 MB
    float* hcsq = (float*)(cb_hi + K_CB * D_DIM);   // 32 KB
    u64* winner = (u64*)(hcsq + K_CB);              // 128 KB (8-byte aligned)
    u32* cnt    = (u32*)(winner + N_ROWS);          // 512 B

    vq_prep_kernel<<<K_CB / 8, 256, 0, stream>>>(cb, cb_hi, hcsq, cnt);

    dim3 g1(N_ROWS / 128, NSPLIT);                  // 128 x 8 = 1024 blocks of 256 thr
    vq_mfma_kernel<<<g1, BLKT, 0, stream>>>(enc, cb, cb_hi, hcsq, winner, cnt, out);
}

// Round 7
// 137.662 us; speedup vs baseline: 1.3616x; 1.3616x over previous
//
#include <hip/hip_runtime.h>

#define N_ROWS 16384
#define K_CB   8192
#define D_DIM  64
#define NSPLIT 8
#define SPLIT_K (K_CB / NSPLIT)          // 1024
#define NSTEP  (SPLIT_K / 32)            // 32 subtile-steps -> slot = t in [0,32): 5 bits
#define BLKT   256                       // 4 waves per block, 1 m-tile (32 rows) per wave

typedef unsigned short u16;
typedef unsigned int   u32;
typedef unsigned long long u64;
typedef __attribute__((ext_vector_type(8)))  short short8v;  // 8 bf16 (4 VGPRs)
typedef __attribute__((ext_vector_type(16))) float f32x16;   // 32x32 MFMA C/D

static __device__ __forceinline__ u16 f2bf(float f) {        // RNE fp32->bf16
    unsigned u = __float_as_uint(f);
    return (u16)((u + 0x7FFFu + ((u >> 16) & 1u)) >> 16);
}

// ---- kernel 0: codebook prep. bf16 cast + 0.5*||c||^2. 8 rows/block. ----
// Single-product bf16 scoring: residual error (~0.02 std) is absorbed by the
// exact fp32 top-2 rescore (top-score spacing ~2.4 for 8192 gaussian
// codewords: huge margin).
__global__ void vq_prep_kernel(const float* __restrict__ cb,
                               u16* __restrict__ cb_hi, float* __restrict__ hcsq)
{
    const int wave = threadIdx.x >> 6;
    const int lane = threadIdx.x & 63;
#pragma unroll
    for (int rr = 0; rr < 2; ++rr) {
        const int r = blockIdx.x * 8 + wave * 2 + rr;
        const float v = cb[r * D_DIM + lane];
        cb_hi[r * D_DIM + lane] = f2bf(v);
        float d = v * v;
#pragma unroll
        for (int m = 1; m < 64; m <<= 1) d += __shfl_xor(d, m, 64);
        if (lane == 0) hcsq[r] = 0.5f * d;
    }
}

// ---- kernel 1: 32x32x16 MFMA scores, 1 m-tile/wave (32 rows), 4 waves,
//      B DIRECT FROM GLOBAL (no LDS staging, no loop barriers),
//      float-key argmax + exact fp32 top-2 rescore ----
// R7 rationale: R3's 46us had ~3-5x idle vs pipe-busy sums; the structural
// suspects (per-stage __syncthreads vmcnt(0) drain, 1-stage DMA margin,
// cross-wave staging coupling) all exist only because B went through LDS.
// But the staged slice (128KB/block) is L2-resident (FETCH 11.9MB proves
// it) -> Common-mistake #7: don't stage cache-fit data. Each wave loads
// its own B-fragments (identical addresses across waves -> L1 sharing),
// ping-pong double-buffered in registers (named bufs, rule #20), ZERO
// barriers in the loop. R6 lesson: no per-block device fences either.
// score(m,n) = dot(x_m, c_n) - 0.5||c_n||^2 ; argmin dist == argmax score.
// A operand: m=lane&31, k=(lane>>5)*8+j. B operand: n=lane&31, k=(lane>>5)*8+j.
// C/D: col(n)=lane&31, row(m)=(reg&3)+8*(reg>>2)+4*(lane>>5)   [m74/m101].
// Key: bits(score) & ~31 | slot(=t), kept with v_max_f32 (<=31 ulp
// perturbation, absorbed by exact top-2 rescore).
__global__ __launch_bounds__(BLKT, 4) void vq_mfma_kernel(
    const float* __restrict__ enc, const float* __restrict__ cb,
    const u16* __restrict__ cb_hi, const float* __restrict__ hcsq,
    u64* __restrict__ winner)
{
    // LDS: keys[128][33] (4224 u32) | lds_h 4KB (1024 u32) | idxb 256 u32
    // = 21.5 KB/block -> 4 blocks/CU easily. No staging buffers.
    __shared__ __align__(16) u32 smem[5504];
    u32*   keys  = smem;                       // [0, 4224)
    float* lds_h = (float*)(smem + 4224);      // [4224, 5248)
    u32*   idxb  = smem + 5248;                // [5248, 5504)

    const int tid  = threadIdx.x;
    const int w    = tid >> 6;                             // 0..3
    const int lane = tid & 63;
    const int n32  = lane & 31;
    const int lh   = lane >> 5;
    const int B0   = blockIdx.y * SPLIT_K;
    const int rowbase = blockIdx.x * 128 + w * 32;         // 32 m-rows per wave

    // ---- A fragments: 1 m-tile x 4 k-chunks, converted once ----
    short8v a_hi[4];
    {
        const float* arow = enc + (size_t)(rowbase + n32) * D_DIM + lh * 8;
#pragma unroll
        for (int c = 0; c < 4; ++c) {
            const float4 u0 = ((const float4*)(arow + c * 16))[0];
            const float4 u1 = ((const float4*)(arow + c * 16))[1];
            const float vv[8] = {u0.x,u0.y,u0.z,u0.w,u1.x,u1.y,u1.z,u1.w};
            short8v h8;
#pragma unroll
            for (int j = 0; j < 8; ++j) h8[j] = (short)f2bf(vv[j]);
            a_hi[c] = h8;
        }
    }

    // ---- split's hcsq into LDS (once); single barrier pre-loop ----
#pragma unroll
    for (int i = 0; i < SPLIT_K / BLKT; ++i)               // 4 iters
        lds_h[tid + i * BLKT] = hcsq[B0 + tid + i * BLKT];
    __syncthreads();

    // ---- per-lane B base: chunk c of step t at gb + t*2048 + c*16 (u16) ----
    // lane reads B[t*32+n32][16c + lh*8 + j]: 16B dwordx4, 32B-contig pairs.
    const u16* gb = cb_hi + (size_t)B0 * D_DIM + (size_t)n32 * D_DIM + lh * 8;

    short8v bhA[4], bhB[4];                                // named ping-pong
#pragma unroll
    for (int c = 0; c < 4; ++c) bhA[c] = *(const short8v*)(gb + c * 16);

    f32x16 z;
#pragma unroll
    for (int r = 0; r < 16; ++r) z[r] = 0.f;               // never written: chain seed

    float bkey[16];
#pragma unroll
    for (int r = 0; r < 16; ++r) bkey[r] = -INFINITY;

    for (int t = 0; t < NSTEP; t += 2) {
        // prefetch step t+1 into B while computing A
        {
            const u16* g1 = gb + (size_t)(t + 1) * 2048;
#pragma unroll
            for (int c = 0; c < 4; ++c) bhB[c] = *(const short8v*)(g1 + c * 16);
        }
        {
            f32x16 acc;
            acc = __builtin_amdgcn_mfma_f32_32x32x16_bf16(a_hi[0], bhA[0], z,   0,0,0);
            acc = __builtin_amdgcn_mfma_f32_32x32x16_bf16(a_hi[1], bhA[1], acc, 0,0,0);
            acc = __builtin_amdgcn_mfma_f32_32x32x16_bf16(a_hi[2], bhA[2], acc, 0,0,0);
            acc = __builtin_amdgcn_mfma_f32_32x32x16_bf16(a_hi[3], bhA[3], acc, 0,0,0);
            const float h = lds_h[t * 32 + n32];
#pragma unroll
            for (int r = 0; r < 16; ++r) {
                const float sc = acc[r] - h;
                const u32 kb = (__float_as_uint(sc) & 0xFFFFFFE0u) | (u32)t;
                bkey[r] = fmaxf(bkey[r], __uint_as_float(kb));
            }
        }
        // prefetch step t+2 into A while computing B
        if (t + 2 < NSTEP) {
            const u16* g2 = gb + (size_t)(t + 2) * 2048;
#pragma unroll
            for (int c = 0; c < 4; ++c) bhA[c] = *(const short8v*)(g2 + c * 16);
        }
        {
            f32x16 acc;
            acc = __builtin_amdgcn_mfma_f32_32x32x16_bf16(a_hi[0], bhB[0], z,   0,0,0);
            acc = __builtin_amdgcn_mfma_f32_32x32x16_bf16(a_hi[1], bhB[1], acc, 0,0,0);
            acc = __builtin_amdgcn_mfma_f32_32x32x16_bf16(a_hi[2], bhB[2], acc, 0,0,0);
            acc = __builtin_amdgcn_mfma_f32_32x32x16_bf16(a_hi[3], bhB[3], acc, 0,0,0);
            const float h = lds_h[(t + 1) * 32 + n32];
#pragma unroll
            for (int r = 0; r < 16; ++r) {
                const float sc = acc[r] - h;
                const u32 kb = (__float_as_uint(sc) & 0xFFFFFFE0u) | (u32)(t + 1);
                bkey[r] = fmaxf(bkey[r], __uint_as_float(kb));
            }
        }
    }

    // ---- per-class winners -> keys[row][cls] in LDS ----
#pragma unroll
    for (int r = 0; r < 16; ++r) {
        const int m = (r & 3) + 8 * (r >> 2) + 4 * lh;
        keys[(w * 32 + m) * 33 + n32] = __float_as_uint(bkey[r]);
    }
    __syncthreads();

    // ---- top-2 of 32 classes (1 thread per row), handoff via LDS ----
    if (tid < 128) {
        float k1 = -INFINITY, k2 = -INFINITY; int c1i = 0, c2i = 0;
#pragma unroll
        for (int cls = 0; cls < 32; ++cls) {
            const float kf = __uint_as_float(keys[tid * 33 + cls]);
            if (kf > k1)      { k2 = k1; c2i = c1i; k1 = kf; c1i = cls; }
            else if (kf > k2) { k2 = kf; c2i = cls; }
        }
        idxb[tid * 2 + 0] = (u32)(B0 + (int)(__float_as_uint(k1) & 31u) * 32 + c1i);
        idxb[tid * 2 + 1] = (u32)(B0 + (int)(__float_as_uint(k2) & 31u) * 32 + c2i);
    }
    __syncthreads();

    // ---- exact fp32 rescore, 2 threads/row (one candidate each) ----
    {
        const int row  = tid >> 1;
        const int grow = blockIdx.x * 128 + row;
        const int idx  = (int)idxb[tid];

        const float4* xp  = (const float4*)(enc + (size_t)grow * D_DIM);
        const float4* cp4 = (const float4*)(cb + (size_t)idx  * D_DIM);
        float d = 0.f;
#pragma unroll
        for (int i = 0; i < 16; ++i) {
            const float4 xv = xp[i], v = cp4[i];
            float t2;
            t2 = xv.x - v.x; d = fmaf(t2, t2, d);
            t2 = xv.y - v.y; d = fmaf(t2, t2, d);
            t2 = xv.z - v.z; d = fmaf(t2, t2, d);
            t2 = xv.w - v.w; d = fmaf(t2, t2, d);
        }
        // (distbits, idx) packed: u64 min == (min dist, then min idx) = jnp first-min.
        // 0xAAAA... ws poison exceeds any packed value (dist sign bit 0): free sentinel.
        atomicMin(winner + grow, ((u64)__float_as_uint(d) << 32) | (u32)idx);
    }
}

// ---- kernel 2: gather winning codeword rows ----
__global__ void vq_gather_kernel(const float* __restrict__ cb,
                                 const u64* __restrict__ winner,
                                 float* __restrict__ out)
{
    const int g   = blockIdx.x * 256 + threadIdx.x;    // 262144 threads x 16B
    const int row = g >> 4;
    const int c4  = g & 15;
    const int idx = (int)(winner[row] & 0xFFFFFFFFu);
    ((float4*)(out + (size_t)row * D_DIM))[c4] =
        ((const float4*)(cb + (size_t)idx * D_DIM))[c4];
}

extern "C" void kernel_launch(void* const* d_in, const int* in_sizes, int n_in,
                              void* d_out, int out_size, void* d_ws, size_t ws_size,
                              hipStream_t stream) {
    const float* enc = (const float*)d_in[0];   // 16384 x 64 fp32
    const float* cb  = (const float*)d_in[1];   // 8192 x 64 fp32
    float* out = (float*)d_out;

    // ws layout (~1.16 MB): cb_hi | hcsq | winner
    u16* cb_hi  = (u16*)d_ws;                       // 1 MB
    float* hcsq = (float*)(cb_hi + K_CB * D_DIM);   // 32 KB
    u64* winner = (u64*)(hcsq + K_CB);              // 128 KB (8-byte aligned)

    vq_prep_kernel<<<K_CB / 8, 256, 0, stream>>>(cb, cb_hi, hcsq);

    dim3 g1(N_ROWS / 128, NSPLIT);                  // 128 x 8 = 1024 blocks of 256 thr
    vq_mfma_kernel<<<g1, BLKT, 0, stream>>>(enc, cb, cb_hi, hcsq, winner);

    vq_gather_kernel<<<(N_ROWS * 16) / 256, 256, 0, stream>>>(cb, winner, out);
}

// Round 8
// 135.729 us; speedup vs baseline: 1.3810x; 1.0142x over previous
//
#include <hip/hip_runtime.h>

#define N_ROWS 16384
#define K_CB   8192
#define D_DIM  64
#define NSPLIT 16
#define SPLIT_K (K_CB / NSPLIT)          // 512
#define STAGE  64                        // codebook rows per LDS stage (two 32-n tiles)
#define NSTAGES (SPLIT_K / STAGE)        // 8  -> slot = 2*s+u in [0,16): 4 bits
#define BLKT   256                       // 4 waves, 2 m-tiles/wave -> 256 rows/block

typedef unsigned short u16;
typedef unsigned int   u32;
typedef unsigned long long u64;
typedef __attribute__((ext_vector_type(8)))  short short8v;  // 8 bf16 (4 VGPRs)
typedef __attribute__((ext_vector_type(16))) float f32x16;   // 32x32 MFMA C/D

static __device__ __forceinline__ u16 f2bf(float f) {        // RNE fp32->bf16
    unsigned u = __float_as_uint(f);
    return (u16)((u + 0x7FFFu + ((u >> 16) & 1u)) >> 16);
}

// ---- kernel 0: codebook prep. bf16 cast + 0.5*||c||^2. 8 rows/block. ----
// Single-product bf16 scoring: residual error (~0.02 std) is absorbed by the
// exact fp32 top-2 rescore (top-score spacing ~2.4 for 8192 gaussian
// codewords: huge margin).
__global__ void vq_prep_kernel(const float* __restrict__ cb,
                               u16* __restrict__ cb_hi, float* __restrict__ hcsq)
{
    const int wave = threadIdx.x >> 6;
    const int lane = threadIdx.x & 63;
#pragma unroll
    for (int rr = 0; rr < 2; ++rr) {
        const int r = blockIdx.x * 8 + wave * 2 + rr;
        const float v = cb[r * D_DIM + lane];
        cb_hi[r * D_DIM + lane] = f2bf(v);
        float d = v * v;
#pragma unroll
        for (int m = 1; m < 64; m <<= 1) d += __shfl_xor(d, m, 64);
        if (lane == 0) hcsq[r] = 0.5f * d;
    }
}

// ---- kernel 1: 32x32x16 MFMA scores, 2 m-tiles/wave (64 rows), 4 waves,
//      -h accumulator seed, float-key argmax + exact fp32 top-2 rescore ----
// R8 rationale: R3 is per-wave dependency-latency bound (issue-busy ~35%
// incl. MFMA; each wave chain ds_read->4 MFMA->48 VALU has no independent
// work to overlap). 2 m-tiles/wave doubles ILP: mt0's key-update VALU
// overlaps mt1's MFMA chain; each B-fragment feeds 8 MFMAs (ds_read/score
// halves). Register-feasible now (no a_lo): a_hi 32 + bkey 32 + bh 16 +
// acc 16 ~ 108 < 128 cap. Seed acc with -h (not 0): kills the persistent
// z (16 regs) AND moves the h-subtract off the post-MFMA critical path.
// Block covers 256 rows -> NSPLIT=16 keeps grid at 1024 blocks (R5: per-
// block overhead scales with block COUNT; count unchanged here).
// R6 lesson: no device-scope fences. R7 lesson: keep LDS staging.
// score(m,n) = dot(x_m, c_n) - 0.5||c_n||^2 ; argmin dist == argmax score.
// A operand: m=lane&31, k=(lane>>5)*8+j. B operand: n=lane&31, k=(lane>>5)*8+j.
// C/D: col(n)=lane&31, row(m)=(reg&3)+8*(reg>>2)+4*(lane>>5)   [m74/m101].
// Key: bits(score) & ~15 | slot, kept with v_max_f32 (<=15 ulp perturbation,
// absorbed by exact top-2 rescore); slot = 2*stage+subtile recovers cidx.
__global__ __launch_bounds__(BLKT, 4) void vq_mfma_kernel(
    const float* __restrict__ enc, const float* __restrict__ cb,
    const u16* __restrict__ cb_hi, const float* __restrict__ hcsq,
    u64* __restrict__ winner)
{
    // loop phase: ldsb 2 bufs x 8KB (4096 u32) | lds_h 2KB (512 u32) = 18 KB
    // epilogue:   keys[256][33] (8448 u32) reuses front (ldsb+lds_h dead);
    //             idxb [8448, 8960). Block LDS = 35840 B -> 4 blocks/CU.
    __shared__ __align__(16) u32 smem[8960];
    u16*   ldsb  = (u16*)smem;                 // [0, 4096) u32 (2 x 4096 u16)
    float* lds_h = (float*)(smem + 4096);      // [4096, 4608) u32
    u32*   keys  = smem;                       // epilogue reuse [0, 8448)
    u32*   idxb  = smem + 8448;                // epilogue [8448, 8960)

    const int tid  = threadIdx.x;
    const int w    = tid >> 6;                             // 0..3
    const int lane = tid & 63;
    const int n32  = lane & 31;
    const int lh   = lane >> 5;
    const int B0   = blockIdx.y * SPLIT_K;
    const int rowbase = blockIdx.x * 256 + w * 64;         // 64 m-rows per wave

    // ---- A fragments: 2 m-tiles x 4 k-chunks, converted once ----
    short8v a_hi[2][4];
#pragma unroll
    for (int mt = 0; mt < 2; ++mt) {
        const float* arow = enc + (size_t)(rowbase + mt * 32 + n32) * D_DIM + lh * 8;
#pragma unroll
        for (int c = 0; c < 4; ++c) {
            const float4 u0 = ((const float4*)(arow + c * 16))[0];
            const float4 u1 = ((const float4*)(arow + c * 16))[1];
            const float vv[8] = {u0.x,u0.y,u0.z,u0.w,u1.x,u1.y,u1.z,u1.w};
            short8v h8;
#pragma unroll
            for (int j = 0; j < 8; ++j) h8[j] = (short)f2bf(vv[j]);
            a_hi[mt][c] = h8;
        }
    }

    // ---- split's hcsq into LDS (once) ----
#pragma unroll
    for (int i = 0; i < SPLIT_K / BLKT; ++i)               // 2 iters
        lds_h[tid + i * BLKT] = hcsq[B0 + tid + i * BLKT];

    // ---- DMA: 8 granules/stage = 4 waves x 2; wave owns (u, c-parity) ----
    // granule slot = lane (n=lane&31, octet=2c+lh) -> contiguous b128 dest.
    const int uu = w & 1;                                  // 32-n subtile
    const int cp = w >> 1;                                 // c parity
    const u16* gbase = cb_hi + (size_t)B0 * D_DIM;

#define DMA_STAGE(buf_, s_)                                                      \
    do {                                                                         \
        _Pragma("unroll")                                                        \
        for (int i_ = 0; i_ < 2; ++i_) {                                         \
            const int c_ = cp + 2 * i_;                                          \
            __builtin_amdgcn_global_load_lds(                                    \
                (const __attribute__((address_space(1))) void*)                  \
                    (gbase + ((size_t)(s_) * STAGE + uu * 32 + n32) * D_DIM      \
                           + (2 * c_ + lh) * 8),                                 \
                (__attribute__((address_space(3))) void*)                        \
                    (ldsb + (buf_) * 4096 + uu * 2048 + c_ * 512),               \
                16, 0, 0);                                                       \
        }                                                                        \
    } while (0)

    DMA_STAGE(0, 0);
    __syncthreads();                                       // stage 0 resident

    float bkey[2][16];
#pragma unroll
    for (int mt = 0; mt < 2; ++mt)
#pragma unroll
        for (int r = 0; r < 16; ++r) bkey[mt][r] = -INFINITY;

    for (int s = 0; s < NSTAGES; ++s) {
        const int buf = s & 1;
        DMA_STAGE(buf ^ 1, (s + 1) & (NSTAGES - 1));       // async prefetch (wrap ok)

#pragma unroll
        for (int u = 0; u < 2; ++u) {                      // two 32-n subtiles
            const u16* bb = ldsb + buf * 4096 + u * 2048;
            short8v bh[4];
#pragma unroll
            for (int c = 0; c < 4; ++c)
                bh[c] = *(const short8v*)(bb + c * 512 + lane * 8);
            const float nh = -lds_h[s * STAGE + u * 32 + n32];
            const u32 slot = (u32)(s * 2 + u);             // 4 bits

#pragma unroll
            for (int mt = 0; mt < 2; ++mt) {               // 2 independent chains:
                f32x16 acc;                                // keys(mt0) || mfma(mt1)
#pragma unroll
                for (int r = 0; r < 16; ++r) acc[r] = nh;  // -h seed (pre-chain)
                acc = __builtin_amdgcn_mfma_f32_32x32x16_bf16(a_hi[mt][0], bh[0], acc, 0,0,0);
                acc = __builtin_amdgcn_mfma_f32_32x32x16_bf16(a_hi[mt][1], bh[1], acc, 0,0,0);
                acc = __builtin_amdgcn_mfma_f32_32x32x16_bf16(a_hi[mt][2], bh[2], acc, 0,0,0);
                acc = __builtin_amdgcn_mfma_f32_32x32x16_bf16(a_hi[mt][3], bh[3], acc, 0,0,0);

#pragma unroll
                for (int r = 0; r < 16; ++r) {             // 2 ops on critical path
                    const u32 kb = (__float_as_uint(acc[r]) & 0xFFFFFFF0u) | slot;
                    bkey[mt][r] = fmaxf(bkey[mt][r], __uint_as_float(kb));
                }
            }
        }
        __syncthreads();   // all waves done reading buf; prefetch drained (vmcnt0)
    }
#undef DMA_STAGE

    // ---- per-class winners -> keys[row][cls] in LDS (reuses ldsb region) ----
#pragma unroll
    for (int mt = 0; mt < 2; ++mt)
#pragma unroll
        for (int r = 0; r < 16; ++r) {
            const int m = (r & 3) + 8 * (r >> 2) + 4 * lh;
            keys[(w * 64 + mt * 32 + m) * 33 + n32] = __float_as_uint(bkey[mt][r]);
        }
    __syncthreads();

    // ---- top-2 of 32 classes (1 thread per row = 256 rows) ----
    {
        float k1 = -INFINITY, k2 = -INFINITY; int c1i = 0, c2i = 0;
#pragma unroll
        for (int cls = 0; cls < 32; ++cls) {
            const float kf = __uint_as_float(keys[tid * 33 + cls]);
            if (kf > k1)      { k2 = k1; c2i = c1i; k1 = kf; c1i = cls; }
            else if (kf > k2) { k2 = kf; c2i = cls; }
        }
        idxb[tid * 2 + 0] = (u32)(B0 + (int)(__float_as_uint(k1) & 15u) * 32 + c1i);
        idxb[tid * 2 + 1] = (u32)(B0 + (int)(__float_as_uint(k2) & 15u) * 32 + c2i);
    }
    __syncthreads();

    // ---- exact fp32 rescore: 512 candidates, 2 per thread ----
#pragma unroll
    for (int k = 0; k < 2; ++k) {
        const int cand = tid + k * 256;
        const int row  = cand >> 1;
        const int grow = blockIdx.x * 256 + row;
        const int idx  = (int)idxb[cand];

        const float4* xp  = (const float4*)(enc + (size_t)grow * D_DIM);
        const float4* cp4 = (const float4*)(cb + (size_t)idx  * D_DIM);
        float d = 0.f;
#pragma unroll
        for (int i = 0; i < 16; ++i) {
            const float4 xv = xp[i], v = cp4[i];
            float t;
            t = xv.x - v.x; d = fmaf(t, t, d);
            t = xv.y - v.y; d = fmaf(t, t, d);
            t = xv.z - v.z; d = fmaf(t, t, d);
            t = xv.w - v.w; d = fmaf(t, t, d);
        }
        // (distbits, idx) packed: u64 min == (min dist, then min idx) = jnp first-min.
        // 0xAAAA... ws poison exceeds any packed value (dist sign bit 0): free sentinel.
        atomicMin(winner + grow, ((u64)__float_as_uint(d) << 32) | (u32)idx);
    }
}

// ---- kernel 2: gather winning codeword rows ----
__global__ void vq_gather_kernel(const float* __restrict__ cb,
                                 const u64* __restrict__ winner,
                                 float* __restrict__ out)
{
    const int g   = blockIdx.x * 256 + threadIdx.x;    // 262144 threads x 16B
    const int row = g >> 4;
    const int c4  = g & 15;
    const int idx = (int)(winner[row] & 0xFFFFFFFFu);
    ((float4*)(out + (size_t)row * D_DIM))[c4] =
        ((const float4*)(cb + (size_t)idx * D_DIM))[c4];
}

extern "C" void kernel_launch(void* const* d_in, const int* in_sizes, int n_in,
                              void* d_out, int out_size, void* d_ws, size_t ws_size,
                              hipStream_t stream) {
    const float* enc = (const float*)d_in[0];   // 16384 x 64 fp32
    const float* cb  = (const float*)d_in[1];   // 8192 x 64 fp32
    float* out = (float*)d_out;

    // ws layout (~1.16 MB): cb_hi | hcsq | winner
    u16* cb_hi  = (u16*)d_ws;                       // 1 MB
    float* hcsq = (float*)(cb_hi + K_CB * D_DIM);   // 32 KB
    u64* winner = (u64*)(hcsq + K_CB);              // 128 KB (8-byte aligned)

    vq_prep_kernel<<<K_CB / 8, 256, 0, stream>>>(cb, cb_hi, hcsq);

    dim3 g1(N_ROWS / 256, NSPLIT);                  // 64 x 16 = 1024 blocks of 256 thr
    vq_mfma_kernel<<<g1, BLKT, 0, stream>>>(enc, cb, cb_hi, hcsq, winner);

    vq_gather_kernel<<<(N_ROWS * 16) / 256, 256, 0, stream>>>(cb, winner, out);
}

// Round 9
// 100.814 us; speedup vs baseline: 1.8593x; 1.3463x over previous
//
#include <hip/hip_runtime.h>

#define N_ROWS 16384
#define K_CB   8192
#define D_DIM  64
#define NSPLIT 8
#define SPLIT_K (K_CB / NSPLIT)          // 1024
#define STAGE  64                        // codebook rows per LDS stage (two 32-n tiles)
#define NSTAGES (SPLIT_K / STAGE)        // 16  -> slot = 2*s+u in [0,32): 5 bits
#define BLKT   256                       // 4 waves per block, 1 m-tile (32 rows) per wave

typedef unsigned short u16;
typedef unsigned int   u32;
typedef unsigned long long u64;
typedef __attribute__((ext_vector_type(8)))  short short8v;  // 8 bf16 (4 VGPRs)
typedef __attribute__((ext_vector_type(16))) float f32x16;   // 32x32 MFMA C/D

static __device__ __forceinline__ u16 f2bf(float f) {        // RNE fp32->bf16
    unsigned u = __float_as_uint(f);
    return (u16)((u + 0x7FFFu + ((u >> 16) & 1u)) >> 16);
}

// ---- kernel 0: codebook prep. bf16 cast + 0.5*||c||^2. 8 rows/block. ----
// Single-product bf16 scoring: residual error (~0.02 std) is absorbed by the
// exact fp32 top-2 rescore (top-score spacing ~2.4 for 8192 gaussian
// codewords: huge margin).
__global__ void vq_prep_kernel(const float* __restrict__ cb,
                               u16* __restrict__ cb_hi, float* __restrict__ hcsq)
{
    const int wave = threadIdx.x >> 6;
    const int lane = threadIdx.x & 63;
#pragma unroll
    for (int rr = 0; rr < 2; ++rr) {
        const int r = blockIdx.x * 8 + wave * 2 + rr;
        const float v = cb[r * D_DIM + lane];
        cb_hi[r * D_DIM + lane] = f2bf(v);
        float d = v * v;
#pragma unroll
        for (int m = 1; m < 64; m <<= 1) d += __shfl_xor(d, m, 64);
        if (lane == 0) hcsq[r] = 0.5f * d;
    }
}

// ---- kernel 1: 32x32x16 MFMA scores, 1 m-tile/wave, 4 waves, 3-deep
//      counted-vmcnt pipeline (T3/T4), -h seed, float-key argmax +
//      exact fp32 top-2 rescore ----
// R9 rationale: R3's per-stage __syncthreads drains vmcnt(0) -> every stage
// waits for the stage+1 DMA (~600-900cy incl. L2 BW) behind a ~400cy compute
// phase: several hundred idle cycles x 16 stages with ALL waves parked.
// Fix = guide T4: never drain vmcnt to 0 in the loop. 3 LDS bufs; issue
// stage s+2 at top; compute stage s; then s_waitcnt vmcnt(2) (stage s+1's
// own 2 loads done; s+2's stay in flight) + raw s_barrier. Loads get a full
// stage of flight. Overwrite-safe: s+2's buf was last read at s-1, behind a
// barrier. Tail wraps harmlessly; one full __syncthreads before epilogue
// drains strays. Also: acc seeded with -h (R8's good fragment: kills the
// persistent z regs, subtract moves off the post-MFMA dependent path).
// Registers: ~70 persistent+transient < 128 cap. R2/R4/R8 lesson: watch
// WRITE_SIZE ~4MB as the spill tripwire.
// score(m,n) = dot(x_m, c_n) - 0.5||c_n||^2 ; argmin dist == argmax score.
// A operand: m=lane&31, k=(lane>>5)*8+j. B operand: n=lane&31, k=(lane>>5)*8+j.
// C/D: col(n)=lane&31, row(m)=(reg&3)+8*(reg>>2)+4*(lane>>5)   [m74/m101].
// Key: bits(score) & ~31 | slot, kept with v_max_f32 (<=31 ulp perturbation,
// absorbed by exact top-2 rescore); slot = 2*stage+subtile recovers cidx.
__global__ __launch_bounds__(BLKT, 4) void vq_mfma_kernel(
    const float* __restrict__ enc, const float* __restrict__ cb,
    const u16* __restrict__ cb_hi, const float* __restrict__ hcsq,
    u64* __restrict__ winner)
{
    // loop phase: ldsb 3 bufs x 8KB (6144 u32) | lds_h 4KB (1024 u32) = 28 KB
    // epilogue:   keys[128][33] (4224 u32) reuses ldsb front; idxb after lds_h.
    // Block LDS = 29696 B -> 4 blocks/CU (reg-limited), 5 LDS-wise.
    __shared__ __align__(16) u32 smem[7424];
    u16*   ldsb  = (u16*)smem;                 // [0, 6144) u32 = 3 x 4096 u16
    float* lds_h = (float*)(smem + 6144);      // [6144, 7168) u32
    u32*   keys  = smem;                       // epilogue reuse [0, 4224)
    u32*   idxb  = smem + 7168;                // epilogue [7168, 7424)

    const int tid  = threadIdx.x;
    const int w    = tid >> 6;                             // 0..3
    const int lane = tid & 63;
    const int n32  = lane & 31;
    const int lh   = lane >> 5;
    const int B0   = blockIdx.y * SPLIT_K;
    const int rowbase = blockIdx.x * 128 + w * 32;         // 32 m-rows per wave

    // ---- A fragments: 1 m-tile x 4 k-chunks, converted once ----
    short8v a_hi[4];
    {
        const float* arow = enc + (size_t)(rowbase + n32) * D_DIM + lh * 8;
#pragma unroll
        for (int c = 0; c < 4; ++c) {
            const float4 u0 = ((const float4*)(arow + c * 16))[0];
            const float4 u1 = ((const float4*)(arow + c * 16))[1];
            const float vv[8] = {u0.x,u0.y,u0.z,u0.w,u1.x,u1.y,u1.z,u1.w};
            short8v h8;
#pragma unroll
            for (int j = 0; j < 8; ++j) h8[j] = (short)f2bf(vv[j]);
            a_hi[c] = h8;
        }
    }

    // ---- split's hcsq into LDS (once, before DMA issues) ----
#pragma unroll
    for (int i = 0; i < SPLIT_K / BLKT; ++i)               // 4 iters
        lds_h[tid + i * BLKT] = hcsq[B0 + tid + i * BLKT];

    // ---- DMA: 8 granules/stage = 4 waves x 2; wave owns (u, c-parity) ----
    // granule slot = lane (n=lane&31, octet=2c+lh) -> contiguous b128 dest.
    const int uu = w & 1;                                  // 32-n subtile
    const int cp = w >> 1;                                 // c parity
    const u16* gbase = cb_hi + (size_t)B0 * D_DIM;

#define DMA_STAGE(buf_, s_)                                                      \
    do {                                                                         \
        _Pragma("unroll")                                                        \
        for (int i_ = 0; i_ < 2; ++i_) {                                         \
            const int c_ = cp + 2 * i_;                                          \
            __builtin_amdgcn_global_load_lds(                                    \
                (const __attribute__((address_space(1))) void*)                  \
                    (gbase + ((size_t)(s_) * STAGE + uu * 32 + n32) * D_DIM      \
                           + (2 * c_ + lh) * 8),                                 \
                (__attribute__((address_space(3))) void*)                        \
                    (ldsb + (buf_) * 4096 + uu * 2048 + c_ * 512),               \
                16, 0, 0);                                                       \
        }                                                                        \
    } while (0)

    // prologue: stages 0 and 1 in flight (2 loads each per thread)
    DMA_STAGE(0, 0);
    DMA_STAGE(1, 1);
    // stage 0 resident (my 2 stage-0 loads done; stage-1's 2 may fly),
    // lds_h ds_writes done; barrier publishes both to all waves.
    asm volatile("s_waitcnt vmcnt(2) lgkmcnt(0)" ::: "memory");
    __builtin_amdgcn_s_barrier();
    __builtin_amdgcn_sched_barrier(0);

    float bkey[16];
#pragma unroll
    for (int r = 0; r < 16; ++r) bkey[r] = -INFINITY;

    int cur = 0;                                           // s % 3
    for (int s = 0; s < NSTAGES; ++s) {
        // issue stage s+2 into the buffer freed at stage s-1 (behind barrier)
        int nbuf = cur + 2; if (nbuf >= 3) nbuf -= 3;
        DMA_STAGE(nbuf, (s + 2) & (NSTAGES - 1));          // tail wraps (stray, drained later)

#pragma unroll
        for (int u = 0; u < 2; ++u) {                      // two 32-n subtiles
            const u16* bb = ldsb + cur * 4096 + u * 2048;
            short8v bh[4];
#pragma unroll
            for (int c = 0; c < 4; ++c)
                bh[c] = *(const short8v*)(bb + c * 512 + lane * 8);
            const float nh = -lds_h[s * STAGE + u * 32 + n32];
            const u32 slot = (u32)(s * 2 + u);             // 5 bits

            f32x16 acc;
#pragma unroll
            for (int r = 0; r < 16; ++r) acc[r] = nh;      // -h seed (dep-free)
            acc = __builtin_amdgcn_mfma_f32_32x32x16_bf16(a_hi[0], bh[0], acc, 0,0,0);
            acc = __builtin_amdgcn_mfma_f32_32x32x16_bf16(a_hi[1], bh[1], acc, 0,0,0);
            acc = __builtin_amdgcn_mfma_f32_32x32x16_bf16(a_hi[2], bh[2], acc, 0,0,0);
            acc = __builtin_amdgcn_mfma_f32_32x32x16_bf16(a_hi[3], bh[3], acc, 0,0,0);

#pragma unroll
            for (int r = 0; r < 16; ++r) {                 // 2 ops on dep path
                const u32 kb = (__float_as_uint(acc[r]) & 0xFFFFFFE0u) | slot;
                bkey[r] = fmaxf(bkey[r], __uint_as_float(kb));
            }
        }

        // counted wait: my stage-(s+1) loads done (stage-(s+2)'s 2 in flight);
        // barrier -> ALL waves' stage-(s+1) loads done -> buf (s+1)%3 resident.
        // NEVER vmcnt(0) here (T4): loads keep a full stage of flight time.
        asm volatile("s_waitcnt vmcnt(2)" ::: "memory");
        __builtin_amdgcn_s_barrier();
        __builtin_amdgcn_sched_barrier(0);

        if (++cur == 3) cur = 0;
    }
#undef DMA_STAGE

    // drain wrapped stray DMA before reusing ldsb as keys (full vmcnt(0) here,
    // once, outside the loop)
    __syncthreads();

    // ---- per-class winners -> keys[row][cls] in LDS (reuses ldsb region) ----
#pragma unroll
    for (int r = 0; r < 16; ++r) {
        const int m = (r & 3) + 8 * (r >> 2) + 4 * lh;
        keys[(w * 32 + m) * 33 + n32] = __float_as_uint(bkey[r]);
    }
    __syncthreads();

    // ---- top-2 of 32 classes (1 thread per row), handoff via LDS ----
    if (tid < 128) {
        float k1 = -INFINITY, k2 = -INFINITY; int c1i = 0, c2i = 0;
#pragma unroll
        for (int cls = 0; cls < 32; ++cls) {
            const float kf = __uint_as_float(keys[tid * 33 + cls]);
            if (kf > k1)      { k2 = k1; c2i = c1i; k1 = kf; c1i = cls; }
            else if (kf > k2) { k2 = kf; c2i = cls; }
        }
        idxb[tid * 2 + 0] = (u32)(B0 + (int)(__float_as_uint(k1) & 31u) * 32 + c1i);
        idxb[tid * 2 + 1] = (u32)(B0 + (int)(__float_as_uint(k2) & 31u) * 32 + c2i);
    }
    __syncthreads();

    // ---- exact fp32 rescore, 2 threads/row (one candidate each) ----
    {
        const int row  = tid >> 1;
        const int grow = blockIdx.x * 128 + row;
        const int idx  = (int)idxb[tid];

        const float4* xp  = (const float4*)(enc + (size_t)grow * D_DIM);
        const float4* cp4 = (const float4*)(cb + (size_t)idx  * D_DIM);
        float d = 0.f;
#pragma unroll
        for (int i = 0; i < 16; ++i) {
            const float4 xv = xp[i], v = cp4[i];
            float t;
            t = xv.x - v.x; d = fmaf(t, t, d);
            t = xv.y - v.y; d = fmaf(t, t, d);
            t = xv.z - v.z; d = fmaf(t, t, d);
            t = xv.w - v.w; d = fmaf(t, t, d);
        }
        // (distbits, idx) packed: u64 min == (min dist, then min idx) = jnp first-min.
        // 0xAAAA... ws poison exceeds any packed value (dist sign bit 0): free sentinel.
        atomicMin(winner + grow, ((u64)__float_as_uint(d) << 32) | (u32)idx);
    }
}

// ---- kernel 2: gather winning codeword rows ----
__global__ void vq_gather_kernel(const float* __restrict__ cb,
                                 const u64* __restrict__ winner,
                                 float* __restrict__ out)
{
    const int g   = blockIdx.x * 256 + threadIdx.x;    // 262144 threads x 16B
    const int row = g >> 4;
    const int c4  = g & 15;
    const int idx = (int)(winner[row] & 0xFFFFFFFFu);
    ((float4*)(out + (size_t)row * D_DIM))[c4] =
        ((const float4*)(cb + (size_t)idx * D_DIM))[c4];
}

extern "C" void kernel_launch(void* const* d_in, const int* in_sizes, int n_in,
                              void* d_out, int out_size, void* d_ws, size_t ws_size,
                              hipStream_t stream) {
    const float* enc = (const float*)d_in[0];   // 16384 x 64 fp32
    const float* cb  = (const float*)d_in[1];   // 8192 x 64 fp32
    float* out = (float*)d_out;

    // ws layout (~1.16 MB): cb_hi | hcsq | winner
    u16* cb_hi  = (u16*)d_ws;                       // 1 MB
    float* hcsq = (float*)(cb_hi + K_CB * D_DIM);   // 32 KB
    u64* winner = (u64*)(hcsq + K_CB);              // 128 KB (8-byte aligned)

    vq_prep_kernel<<<K_CB / 8, 256, 0, stream>>>(cb, cb_hi, hcsq);

    dim3 g1(N_ROWS / 128, NSPLIT);                  // 128 x 8 = 1024 blocks of 256 thr
    vq_mfma_kernel<<<g1, BLKT, 0, stream>>>(enc, cb, cb_hi, hcsq, winner);

    vq_gather_kernel<<<(N_ROWS * 16) / 256, 256, 0, stream>>>(cb, winner, out);
}

// Round 10
// 96.803 us; speedup vs baseline: 1.9363x; 1.0414x over previous
//
#include <hip/hip_runtime.h>

#define N_ROWS 16384
#define K_CB   8192
#define D_DIM  64
#define NSPLIT 4
#define SPLIT_K (K_CB / NSPLIT)          // 2048
#define STAGE  64                        // codebook rows per LDS stage (two 32-n tiles)
#define NSTAGES (SPLIT_K / STAGE)        // 32  -> slot = 2*s+u in [0,64): 6 bits
#define BLKT   256                       // 4 waves per block, 1 m-tile (32 rows) per wave

typedef unsigned short u16;
typedef unsigned int   u32;
typedef unsigned long long u64;
typedef __attribute__((ext_vector_type(8)))  short short8v;  // 8 bf16 (4 VGPRs)
typedef __attribute__((ext_vector_type(16))) float f32x16;   // 32x32 MFMA C/D

static __device__ __forceinline__ u16 f2bf(float f) {        // RNE fp32->bf16
    unsigned u = __float_as_uint(f);
    return (u16)((u + 0x7FFFu + ((u >> 16) & 1u)) >> 16);
}

// ---- kernel 0: codebook prep. bf16 cast + 0.5*||c||^2. 8 rows/block. ----
// Single-product bf16 scoring: residual error (~0.02 std) is absorbed by the
// exact fp32 top-2 rescore (top-score spacing ~2.4 for 8192 gaussian
// codewords: huge margin).
__global__ void vq_prep_kernel(const float* __restrict__ cb,
                               u16* __restrict__ cb_hi, float* __restrict__ hcsq)
{
    const int wave = threadIdx.x >> 6;
    const int lane = threadIdx.x & 63;
#pragma unroll
    for (int rr = 0; rr < 2; ++rr) {
        const int r = blockIdx.x * 8 + wave * 2 + rr;
        const float v = cb[r * D_DIM + lane];
        cb_hi[r * D_DIM + lane] = f2bf(v);
        float d = v * v;
#pragma unroll
        for (int m = 1; m < 64; m <<= 1) d += __shfl_xor(d, m, 64);
        if (lane == 0) hcsq[r] = 0.5f * d;
    }
}

// ---- kernel 1: 32x32x16 MFMA scores, 1 m-tile/wave, 4 waves, 3-deep
//      counted-vmcnt pipeline, -h seed, float-key argmax + exact top-2 ----
// R10 = R9 body + NSPLIT 8->4 ONLY. Measured model (R3/R5/R9): wall =
// loop(25.8us, per-CU invariant) + blocks/CU x O(5.1us per resident block:
// A-frag cold loads+convert, prologue drain, keys/top-2/rescore epilogue,
// atomics). 2 blocks/CU -> predicted ~36us. Occupancy WILL read low
// (~15%): expected, not a regression signal here. Slot widens to 6 bits
// (<=63 ulp key perturbation, absorbed by exact top-2 rescore).
// R2/R4/R8 lesson: never grow persistent regs (spill cliff). R6: no device
// fences. R7: keep LDS staging.
// score(m,n) = dot(x_m, c_n) - 0.5||c_n||^2 ; argmin dist == argmax score.
// A operand: m=lane&31, k=(lane>>5)*8+j. B operand: n=lane&31, k=(lane>>5)*8+j.
// C/D: col(n)=lane&31, row(m)=(reg&3)+8*(reg>>2)+4*(lane>>5)   [m74/m101].
__global__ __launch_bounds__(BLKT, 4) void vq_mfma_kernel(
    const float* __restrict__ enc, const float* __restrict__ cb,
    const u16* __restrict__ cb_hi, const float* __restrict__ hcsq,
    u64* __restrict__ winner)
{
    // loop phase: ldsb 3 bufs x 8KB (6144 u32) | lds_h 8KB (2048 u32) = 32 KB
    // epilogue:   keys[128][33] (4224 u32) reuses ldsb front; idxb at 8192.
    // Block LDS = 33792 B; grid puts only 2 blocks/CU anyway.
    __shared__ __align__(16) u32 smem[8448];
    u16*   ldsb  = (u16*)smem;                 // [0, 6144) u32 = 3 x 4096 u16
    float* lds_h = (float*)(smem + 6144);      // [6144, 8192) u32
    u32*   keys  = smem;                       // epilogue reuse [0, 4224)
    u32*   idxb  = smem + 8192;                // epilogue [8192, 8448)

    const int tid  = threadIdx.x;
    const int w    = tid >> 6;                             // 0..3
    const int lane = tid & 63;
    const int n32  = lane & 31;
    const int lh   = lane >> 5;
    const int B0   = blockIdx.y * SPLIT_K;
    const int rowbase = blockIdx.x * 128 + w * 32;         // 32 m-rows per wave

    // ---- A fragments: 1 m-tile x 4 k-chunks, converted once ----
    short8v a_hi[4];
    {
        const float* arow = enc + (size_t)(rowbase + n32) * D_DIM + lh * 8;
#pragma unroll
        for (int c = 0; c < 4; ++c) {
            const float4 u0 = ((const float4*)(arow + c * 16))[0];
            const float4 u1 = ((const float4*)(arow + c * 16))[1];
            const float vv[8] = {u0.x,u0.y,u0.z,u0.w,u1.x,u1.y,u1.z,u1.w};
            short8v h8;
#pragma unroll
            for (int j = 0; j < 8; ++j) h8[j] = (short)f2bf(vv[j]);
            a_hi[c] = h8;
        }
    }

    // ---- split's hcsq into LDS (once, before DMA issues) ----
#pragma unroll
    for (int i = 0; i < SPLIT_K / BLKT; ++i)               // 8 iters
        lds_h[tid + i * BLKT] = hcsq[B0 + tid + i * BLKT];

    // ---- DMA: 8 granules/stage = 4 waves x 2; wave owns (u, c-parity) ----
    // granule slot = lane (n=lane&31, octet=2c+lh) -> contiguous b128 dest.
    const int uu = w & 1;                                  // 32-n subtile
    const int cp = w >> 1;                                 // c parity
    const u16* gbase = cb_hi + (size_t)B0 * D_DIM;

#define DMA_STAGE(buf_, s_)                                                      \
    do {                                                                         \
        _Pragma("unroll")                                                        \
        for (int i_ = 0; i_ < 2; ++i_) {                                         \
            const int c_ = cp + 2 * i_;                                          \
            __builtin_amdgcn_global_load_lds(                                    \
                (const __attribute__((address_space(1))) void*)                  \
                    (gbase + ((size_t)(s_) * STAGE + uu * 32 + n32) * D_DIM      \
                           + (2 * c_ + lh) * 8),                                 \
                (__attribute__((address_space(3))) void*)                        \
                    (ldsb + (buf_) * 4096 + uu * 2048 + c_ * 512),               \
                16, 0, 0);                                                       \
        }                                                                        \
    } while (0)

    // prologue: stages 0 and 1 in flight (2 loads each per thread)
    DMA_STAGE(0, 0);
    DMA_STAGE(1, 1);
    // stage 0 resident (my 2 stage-0 loads done; stage-1's 2 may fly),
    // lds_h ds_writes done; barrier publishes both to all waves.
    asm volatile("s_waitcnt vmcnt(2) lgkmcnt(0)" ::: "memory");
    __builtin_amdgcn_s_barrier();
    __builtin_amdgcn_sched_barrier(0);

    float bkey[16];
#pragma unroll
    for (int r = 0; r < 16; ++r) bkey[r] = -INFINITY;

    int cur = 0;                                           // s % 3
    for (int s = 0; s < NSTAGES; ++s) {
        // issue stage s+2 into the buffer freed at stage s-1 (behind barrier)
        int nbuf = cur + 2; if (nbuf >= 3) nbuf -= 3;
        DMA_STAGE(nbuf, (s + 2) & (NSTAGES - 1));          // tail wraps (stray, drained later)

#pragma unroll
        for (int u = 0; u < 2; ++u) {                      // two 32-n subtiles
            const u16* bb = ldsb + cur * 4096 + u * 2048;
            short8v bh[4];
#pragma unroll
            for (int c = 0; c < 4; ++c)
                bh[c] = *(const short8v*)(bb + c * 512 + lane * 8);
            const float nh = -lds_h[s * STAGE + u * 32 + n32];
            const u32 slot = (u32)(s * 2 + u);             // 6 bits

            f32x16 acc;
#pragma unroll
            for (int r = 0; r < 16; ++r) acc[r] = nh;      // -h seed (dep-free)
            acc = __builtin_amdgcn_mfma_f32_32x32x16_bf16(a_hi[0], bh[0], acc, 0,0,0);
            acc = __builtin_amdgcn_mfma_f32_32x32x16_bf16(a_hi[1], bh[1], acc, 0,0,0);
            acc = __builtin_amdgcn_mfma_f32_32x32x16_bf16(a_hi[2], bh[2], acc, 0,0,0);
            acc = __builtin_amdgcn_mfma_f32_32x32x16_bf16(a_hi[3], bh[3], acc, 0,0,0);

#pragma unroll
            for (int r = 0; r < 16; ++r) {                 // 2 ops on dep path
                const u32 kb = (__float_as_uint(acc[r]) & 0xFFFFFFC0u) | slot;
                bkey[r] = fmaxf(bkey[r], __uint_as_float(kb));
            }
        }

        // counted wait: my stage-(s+1) loads done (stage-(s+2)'s 2 in flight);
        // barrier -> ALL waves' stage-(s+1) loads done -> buf (s+1)%3 resident.
        asm volatile("s_waitcnt vmcnt(2)" ::: "memory");
        __builtin_amdgcn_s_barrier();
        __builtin_amdgcn_sched_barrier(0);

        if (++cur == 3) cur = 0;
    }
#undef DMA_STAGE

    // drain wrapped stray DMA before reusing ldsb as keys (full vmcnt(0) here,
    // once, outside the loop)
    __syncthreads();

    // ---- per-class winners -> keys[row][cls] in LDS (reuses ldsb region) ----
#pragma unroll
    for (int r = 0; r < 16; ++r) {
        const int m = (r & 3) + 8 * (r >> 2) + 4 * lh;
        keys[(w * 32 + m) * 33 + n32] = __float_as_uint(bkey[r]);
    }
    __syncthreads();

    // ---- top-2 of 32 classes (1 thread per row), handoff via LDS ----
    if (tid < 128) {
        float k1 = -INFINITY, k2 = -INFINITY; int c1i = 0, c2i = 0;
#pragma unroll
        for (int cls = 0; cls < 32; ++cls) {
            const float kf = __uint_as_float(keys[tid * 33 + cls]);
            if (kf > k1)      { k2 = k1; c2i = c1i; k1 = kf; c1i = cls; }
            else if (kf > k2) { k2 = kf; c2i = cls; }
        }
        idxb[tid * 2 + 0] = (u32)(B0 + (int)(__float_as_uint(k1) & 63u) * 32 + c1i);
        idxb[tid * 2 + 1] = (u32)(B0 + (int)(__float_as_uint(k2) & 63u) * 32 + c2i);
    }
    __syncthreads();

    // ---- exact fp32 rescore, 2 threads/row (one candidate each) ----
    {
        const int row  = tid >> 1;
        const int grow = blockIdx.x * 128 + row;
        const int idx  = (int)idxb[tid];

        const float4* xp  = (const float4*)(enc + (size_t)grow * D_DIM);
        const float4* cp4 = (const float4*)(cb + (size_t)idx  * D_DIM);
        float d = 0.f;
#pragma unroll
        for (int i = 0; i < 16; ++i) {
            const float4 xv = xp[i], v = cp4[i];
            float t;
            t = xv.x - v.x; d = fmaf(t, t, d);
            t = xv.y - v.y; d = fmaf(t, t, d);
            t = xv.z - v.z; d = fmaf(t, t, d);
            t = xv.w - v.w; d = fmaf(t, t, d);
        }
        // (distbits, idx) packed: u64 min == (min dist, then min idx) = jnp first-min.
        // 0xAAAA... ws poison exceeds any packed value (dist sign bit 0): free sentinel.
        atomicMin(winner + grow, ((u64)__float_as_uint(d) << 32) | (u32)idx);
    }
}

// ---- kernel 2: gather winning codeword rows ----
__global__ void vq_gather_kernel(const float* __restrict__ cb,
                                 const u64* __restrict__ winner,
                                 float* __restrict__ out)
{
    const int g   = blockIdx.x * 256 + threadIdx.x;    // 262144 threads x 16B
    const int row = g >> 4;
    const int c4  = g & 15;
    const int idx = (int)(winner[row] & 0xFFFFFFFFu);
    ((float4*)(out + (size_t)row * D_DIM))[c4] =
        ((const float4*)(cb + (size_t)idx * D_DIM))[c4];
}

extern "C" void kernel_launch(void* const* d_in, const int* in_sizes, int n_in,
                              void* d_out, int out_size, void* d_ws, size_t ws_size,
                              hipStream_t stream) {
    const float* enc = (const float*)d_in[0];   // 16384 x 64 fp32
    const float* cb  = (const float*)d_in[1];   // 8192 x 64 fp32
    float* out = (float*)d_out;

    // ws layout (~1.16 MB): cb_hi | hcsq | winner
    u16* cb_hi  = (u16*)d_ws;                       // 1 MB
    float* hcsq = (float*)(cb_hi + K_CB * D_DIM);   // 32 KB
    u64* winner = (u64*)(hcsq + K_CB);              // 128 KB (8-byte aligned)

    vq_prep_kernel<<<K_CB / 8, 256, 0, stream>>>(cb, cb_hi, hcsq);

    dim3 g1(N_ROWS / 128, NSPLIT);                  // 128 x 4 = 512 blocks of 256 thr
    vq_mfma_kernel<<<g1, BLKT, 0, stream>>>(enc, cb, cb_hi, hcsq, winner);

    vq_gather_kernel<<<(N_ROWS * 16) / 256, 256, 0, stream>>>(cb, winner, out);
}